// Round 4
// baseline (60.625 us; speedup 1.0000x reference)
//
#include <hip/hip_runtime.h>
#include <climits>
#include <float.h>

#define H_     512
#define W_     512
#define C_     80
#define HW_    (H_ * W_)           // 262144 = 2^18
#define NTOT   (C_ * HW_)          // 20,971,520
#define K_     10
#define R_     16                  // rows per strip
#define NSTRIP (C_ * (H_ / R_) * (W_ / 4))   // 80*32*128 = 327680
#define NBLK   (NSTRIP / 256)                // 1280
#define TAU    0.9999f             // candidate threshold (validity re-checked)

__device__ __forceinline__ float max3f(float a, float b, float c) {
    return fmaxf(fmaxf(a, b), c);
}

// Fully-unrolled bubble insert into descending sorted (tv, ti), tie -> lower idx.
__device__ __forceinline__ void insert10(float (&tv)[K_], int (&ti)[K_],
                                         float s, int ridx) {
#pragma unroll
    for (int j = 0; j < K_; ++j) {
        const bool better = (s > tv[j]) || (s == tv[j] && ridx < ti[j]);
        const float ov = tv[j]; const int oi = ti[j];
        if (better) { tv[j] = s; ti[j] = ridx; s = ov; ridx = oi; }
    }
}

__global__ void k_init(int* cnt) { if (threadIdx.x == 0) *cnt = 0; }

// ---------------------------------------------------------------------------
// k_scan: vertical-strip stencil. One float4 load per row; 3-row context
// rotates through registers. Window math + edge loads only in rare branch.
// ---------------------------------------------------------------------------
__global__ __launch_bounds__(256) void k_scan(const float* __restrict__ kp,
                                              float* __restrict__ cs,
                                              int*   __restrict__ cidx,
                                              int*   __restrict__ cnt,
                                              int cap)
{
    const int s   = blockIdx.x * 256 + threadIdx.x;   // strip id
    const int cls = s >> 12;                          // 4096 strips per plane
    const int r   = s & 4095;
    const int g   = r >> 7;                           // rowgroup (32 per plane)
    const int xc  = r & 127;                          // x-chunk
    const int y0  = g << 4;                           // R_ = 16
    const int x   = xc << 2;

    const float* plane = kp + (cls << 18);
    const float* p     = plane + (y0 << 9) + x;

    float4 rm = *(const float4*)((g > 0) ? (p - W_) : p);   // row y0-1 (clamped)
    float4 rc = *(const float4*)p;                          // row y0

#pragma unroll
    for (int i = 0; i < R_; ++i) {
        const int yn = (y0 + i + 1 < H_) ? (y0 + i + 1) : (H_ - 1);
        const float4 rn = *(const float4*)(plane + (yn << 9) + x);

        // pre-filter: a kept score equals its raw value, so raw > TAU is necessary
        if (__builtin_expect((rc.x > TAU) | (rc.y > TAU) | (rc.z > TAU) | (rc.w > TAU), 0)) {
            const int y   = y0 + i;
            const int ym1 = (y > 0)      ? y - 1 : 0;
            const int yp1 = (y < H_ - 1) ? y + 1 : H_ - 1;
            const int xl  = (x > 0)      ? x - 1 : 0;
            const int xr  = (x + 4 < W_) ? x + 4 : W_ - 1;

            const float la = plane[(ym1 << 9) + xl];
            const float lb = plane[(y   << 9) + xl];
            const float lc = plane[(yp1 << 9) + xl];
            const float ka = plane[(ym1 << 9) + xr];
            const float kb = plane[(y   << 9) + xr];
            const float kc = plane[(yp1 << 9) + xr];

            const float vm0 = max3f(rm.x, rc.x, rn.x);
            const float vm1 = max3f(rm.y, rc.y, rn.y);
            const float vm2 = max3f(rm.z, rc.z, rn.z);
            const float vm3 = max3f(rm.w, rc.w, rn.w);
            const float lv  = (x > 0)      ? max3f(la, lb, lc) : -FLT_MAX;
            const float rv  = (x + 4 < W_) ? max3f(ka, kb, kc) : -FLT_MAX;

            const float w0 = fmaxf(lv, fmaxf(vm0, vm1));
            const float w1 = max3f(vm0, vm1, vm2);
            const float w2 = max3f(vm1, vm2, vm3);
            const float w3 = fmaxf(fmaxf(vm2, vm3), rv);

            const int base = ((y << 9) + x) * C_ + cls;   // ref flat index
            if (rc.x > TAU && rc.x == w0) {
                const int q = atomicAdd(cnt, 1);
                if (q < cap) { cs[q] = rc.x; cidx[q] = base; }
            }
            if (rc.y > TAU && rc.y == w1) {
                const int q = atomicAdd(cnt, 1);
                if (q < cap) { cs[q] = rc.y; cidx[q] = base + C_; }
            }
            if (rc.z > TAU && rc.z == w2) {
                const int q = atomicAdd(cnt, 1);
                if (q < cap) { cs[q] = rc.z; cidx[q] = base + 2 * C_; }
            }
            if (rc.w > TAU && rc.w == w3) {
                const int q = atomicAdd(cnt, 1);
                if (q < cap) { cs[q] = rc.w; cidx[q] = base + 3 * C_; }
            }
        }

        rm = rc;
        rc = rn;
    }
}

// ---------------------------------------------------------------------------
// k_reduce: single block. Valid candidate list (10 <= n <= cap) provably
// contains the global top-10 (10th-best masked score must exceed TAU).
// Otherwise exhaustive fallback. Then decode boxes.
// ---------------------------------------------------------------------------
__global__ __launch_bounds__(256) void k_reduce(const float* __restrict__ cs,
                                                const int*   __restrict__ cidx,
                                                const int*   __restrict__ cnt,
                                                int cap,
                                                const float* __restrict__ kp,
                                                const float* __restrict__ off,
                                                const float* __restrict__ sz,
                                                float* __restrict__ out)
{
    float tv[K_];
    int   ti[K_];
#pragma unroll
    for (int k = 0; k < K_; ++k) { tv[k] = 0.0f; ti[k] = INT_MAX; }

    const int n = *cnt;
    const bool valid = (n >= K_) && (n <= cap);

    if (valid) {
        for (int i = threadIdx.x; i < n; i += 256)
            insert10(tv, ti, cs[i], cidx[i]);
    } else {
        // exhaustive fallback (never taken for the benchmark input)
        float thresh = 0.0f;
        for (int idx = threadIdx.x; idx < NTOT; idx += 256) {
            const int cls = idx >> 18;
            const int sp  = idx & (HW_ - 1);
            const int y   = sp >> 9;
            const int x   = sp & (W_ - 1);
            const float* plane = kp + (cls << 18);
            const float v = plane[sp];
            float wmax = v;
            const int y0 = (y > 0)      ? y - 1 : 0;
            const int y1 = (y < H_ - 1) ? y + 1 : H_ - 1;
            const int x0 = (x > 0)      ? x - 1 : 0;
            const int x1 = (x < W_ - 1) ? x + 1 : W_ - 1;
            for (int yy = y0; yy <= y1; ++yy)
                for (int xx = x0; xx <= x1; ++xx)
                    wmax = fmaxf(wmax, plane[(yy << 9) + xx]);
            if (v == wmax && v > thresh) {
                insert10(tv, ti, v, sp * C_ + cls);
                thresh = tv[K_ - 1];
            }
        }
    }

    // ---- block merge of sorted 10-lists ------------------------------------
    __shared__ float sv[256][K_];
    __shared__ int   si[256][K_];
    const int t = threadIdx.x;
#pragma unroll
    for (int k = 0; k < K_; ++k) { sv[t][k] = tv[k]; si[t][k] = ti[k]; }
    __syncthreads();

    for (int stride = 128; stride > 0; stride >>= 1) {
        if (t < stride) {
            float mv[K_]; int mi[K_];
            int a = 0, b = 0;
#pragma unroll
            for (int k = 0; k < K_; ++k) {
                const float va = sv[t][a], vb = sv[t + stride][b];
                const int   ia = si[t][a], ib = si[t + stride][b];
                const bool takeA = (va > vb) || (va == vb && ia <= ib);
                if (takeA) { mv[k] = va; mi[k] = ia; ++a; }
                else       { mv[k] = vb; mi[k] = ib; ++b; }
            }
#pragma unroll
            for (int k = 0; k < K_; ++k) { sv[t][k] = mv[k]; si[t][k] = mi[k]; }
        }
        __syncthreads();
    }

    if (t < K_) {
        const float score = sv[0][t];
        const int   index = si[0][t];
        const int   chan  = index / C_;          // y*W + x
        const int   cls   = index - chan * C_;
        const int   y     = chan >> 9;
        const int   x     = chan & (W_ - 1);

        // last-dim flip: y-component <- channel 1, x-component <- channel 0
        const float offy = off[HW_ + chan];
        const float offx = off[chan];
        const float szy  = sz[HW_ + chan];
        const float szx  = sz[chan];

        const float py = (float)y + offy;
        const float px = (float)x + offx;
        const float hy = 0.5f * szy;
        const float hx = 0.5f * szx;

        const float lo = 0.0f, hi = (float)(W_ - 1);
        out[t * 4 + 0] = fminf(fmaxf(py - hy, lo), hi) * 4.0f;
        out[t * 4 + 1] = fminf(fmaxf(px - hx, lo), hi) * 4.0f;
        out[t * 4 + 2] = fminf(fmaxf(py + hy, lo), hi) * 4.0f;
        out[t * 4 + 3] = fminf(fmaxf(px + hx, lo), hi) * 4.0f;
        out[40 + t]    = (float)cls;   // detection_classes
        out[50 + t]    = score;        // detection_scores
    }
}

// ---------------------------------------------------------------------------
extern "C" void kernel_launch(void* const* d_in, const int* in_sizes, int n_in,
                              void* d_out, int out_size, void* d_ws, size_t ws_size,
                              hipStream_t stream)
{
    const float* off = (const float*)d_in[0];   // [1,2,512,512]
    const float* sz  = (const float*)d_in[1];   // [1,2,512,512]
    const float* kp  = (const float*)d_in[2];   // [1,80,512,512]
    float* out = (float*)d_out;                 // 40 + 10 + 10 = 60 floats

    // ws layout: [0..15] counter pad | cs[cap] floats | cidx[cap] ints
    int cap = 8192;
    const size_t avail = (ws_size > 16) ? (ws_size - 16) : 0;
    if ((size_t)cap * 8 > avail) cap = (int)(avail / 8);
    if (cap < 16) cap = 16;

    int*   cnt  = (int*)d_ws;
    float* cs   = (float*)((char*)d_ws + 16);
    int*   cidx = (int*)((char*)d_ws + 16 + (size_t)cap * sizeof(float));

    k_init<<<1, 64, 0, stream>>>(cnt);
    k_scan<<<NBLK, 256, 0, stream>>>(kp, cs, cidx, cnt, cap);
    k_reduce<<<1, 256, 0, stream>>>(cs, cidx, cnt, cap, kp, off, sz, out);
}